// Round 2
// baseline (833.970 us; speedup 1.0000x reference)
//
#include <hip/hip_runtime.h>

#define N_NODES 20000
#define N_EDGES 320000
#define SEQ 8

typedef __attribute__((ext_vector_type(8))) short bf16x8;
typedef __attribute__((ext_vector_type(4))) float floatx4;

__device__ __forceinline__ unsigned short f2bf(float f) {
  unsigned int u = __builtin_bit_cast(unsigned int, f);
  return (unsigned short)((u + 0x7fffu + ((u >> 16) & 1u)) >> 16);
}
__device__ __forceinline__ float bflo(unsigned int u) {
  return __builtin_bit_cast(float, u << 16);
}
__device__ __forceinline__ float bfhi(unsigned int u) {
  return __builtin_bit_cast(float, u & 0xffff0000u);
}
__device__ __forceinline__ float sigf(float x) { return 1.f / (1.f + __expf(-x)); }

// ---------------- setup kernels ----------------

__global__ void k_init(float* __restrict__ deg, int* __restrict__ counts) {
  int i = blockIdx.x * 256 + threadIdx.x;
  if (i < N_NODES) { deg[i] = 1.0f; counts[i] = 0; }
}

__global__ void k_deg(const int* __restrict__ ei, const float* __restrict__ ea,
                      float* __restrict__ deg, int* __restrict__ counts) {
  int e = blockIdx.x * 256 + threadIdx.x;
  if (e >= N_EDGES) return;
  int d = ei[N_EDGES + e];
  atomicAdd(&deg[d], ea[e]);
  atomicAdd(&counts[d], 1);
}

__global__ void k_rsqrt(float* __restrict__ dinv) {
  int i = blockIdx.x * 256 + threadIdx.x;
  if (i < N_NODES) dinv[i] = rsqrtf(dinv[i]);
}

__global__ void k_scan1(const int* __restrict__ counts, int* __restrict__ incl,
                        int* __restrict__ part) {
  __shared__ int sm[256];
  int t = threadIdx.x;
  int g = blockIdx.x * 256 + t;
  int v = (g < N_NODES) ? counts[g] : 0;
  sm[t] = v;
  __syncthreads();
  for (int o = 1; o < 256; o <<= 1) {
    int add = (t >= o) ? sm[t - o] : 0;
    __syncthreads();
    sm[t] += add;
    __syncthreads();
  }
  if (g < N_NODES) incl[g] = sm[t];
  if (t == 255) part[blockIdx.x] = sm[255];
}

__global__ void k_scan2(int* __restrict__ part, int nb) {
  __shared__ int sm[128];
  int t = threadIdx.x;
  int v = (t < nb) ? part[t] : 0;
  sm[t] = v;
  __syncthreads();
  for (int o = 1; o < 128; o <<= 1) {
    int add = (t >= o) ? sm[t - o] : 0;
    __syncthreads();
    sm[t] += add;
    __syncthreads();
  }
  if (t < nb) part[t] = sm[t] - v;  // exclusive
}

__global__ void k_scan3(const int* __restrict__ incl, const int* __restrict__ counts,
                        const int* __restrict__ part, int* __restrict__ row_ptr,
                        int* __restrict__ cursor) {
  int g = blockIdx.x * 256 + threadIdx.x;
  if (g < N_NODES) {
    int start = incl[g] - counts[g] + part[blockIdx.x];
    row_ptr[g] = start;
    cursor[g] = start;
  }
  if (g == 0) row_ptr[N_NODES] = N_EDGES;
}

__global__ void k_fill(const int* __restrict__ ei, const float* __restrict__ ea,
                       const float* __restrict__ dinv, int* __restrict__ cursor,
                       int* __restrict__ csr_src, float* __restrict__ csr_w) {
  int e = blockIdx.x * 256 + threadIdx.x;
  if (e >= N_EDGES) return;
  int s = ei[e], d = ei[N_EDGES + e];
  int k = atomicAdd(&cursor[d], 1);
  csr_src[k] = s;
  csr_w[k] = dinv[s] * ea[e] * dinv[d];
}

// WiT[n][k] = Wi[k][n] (256x256); WcT[n'][k] = Wc[k][orig(n')] (512x256),
// gate-interleaved: n' = 4*j + gate, orig = gate*128 + j
__global__ void k_prep_w(const float* __restrict__ Wi, const float* __restrict__ Wc,
                         unsigned short* __restrict__ WiT,
                         unsigned short* __restrict__ WcT) {
  int idx = blockIdx.x * 256 + threadIdx.x;  // 0..131071
  if (idx < 65536) {
    int n = idx >> 8, k = idx & 255;
    WiT[n * 256 + k] = f2bf(Wi[k * 256 + n]);
  }
  int n2 = idx >> 8, k = idx & 255;  // n2 0..511
  int orig = ((n2 & 3) << 7) | (n2 >> 2);
  WcT[n2 * 256 + k] = f2bf(Wc[k * 512 + orig]);
}

// hc_bf[i][0..127]=bf16(h[i]), [128..255]=bf16(c[i]); one uint = 2 bf16
__global__ void k_cvt(const float* __restrict__ h, const float* __restrict__ c,
                      unsigned int* __restrict__ hc) {
  int idx = blockIdx.x * 256 + threadIdx.x;  // per uint pair
  if (idx >= N_NODES * 128) return;
  int i = idx >> 7, col = (idx & 127) << 1;
  float a, b;
  if (col < 128) { a = h[i * 128 + col]; b = h[i * 128 + col + 1]; }
  else { a = c[i * 128 + col - 128]; b = c[i * 128 + col - 127]; }
  hc[idx] = (unsigned int)f2bf(a) | ((unsigned int)f2bf(b) << 16);
}

// ---------------- aggregation (gather via CSR, one wave per node) -------------

// init: x = hc_bf rows of 256 bf16 (uint2/lane); out = AhAc full row (uint2/lane)
__global__ __launch_bounds__(256) void k_agg_init(
    const unsigned int* __restrict__ hc, unsigned int* __restrict__ AhAc_u,
    const float* __restrict__ dinv, const int* __restrict__ row_ptr,
    const int* __restrict__ csr_src, const float* __restrict__ csr_w) {
  int wid = (blockIdx.x * 256 + threadIdx.x) >> 6;
  int lane = threadIdx.x & 63;
  if (wid >= N_NODES) return;
  float di = dinv[wid], dd = di * di;
  const uint2* x = (const uint2*)hc;
  uint2 a = x[(size_t)wid * 64 + lane];
  float s0 = bflo(a.x) * dd, s1 = bfhi(a.x) * dd;
  float s2 = bflo(a.y) * dd, s3 = bfhi(a.y) * dd;
  int e = row_ptr[wid], end = row_ptr[wid + 1];
  for (; e < end; ++e) {
    int s = csr_src[e];
    float w = csr_w[e];
    uint2 v = x[(size_t)s * 64 + lane];
    s0 += bflo(v.x) * w; s1 += bfhi(v.x) * w;
    s2 += bflo(v.y) * w; s3 += bfhi(v.y) * w;
  }
  uint2 o;
  o.x = (unsigned int)f2bf(s0) | ((unsigned int)f2bf(s1) << 16);
  o.y = (unsigned int)f2bf(s2) | ((unsigned int)f2bf(s3) << 16);
  ((uint2*)AhAc_u)[(size_t)wid * 64 + lane] = o;
}

// step: x = hbf rows of 128 bf16 (uint/lane); out -> AhAc cols 128..255
__global__ __launch_bounds__(256) void k_agg_step(
    const unsigned int* __restrict__ hbf_u, unsigned int* __restrict__ AhAc_u,
    const float* __restrict__ dinv, const int* __restrict__ row_ptr,
    const int* __restrict__ csr_src, const float* __restrict__ csr_w) {
  int wid = (blockIdx.x * 256 + threadIdx.x) >> 6;
  int lane = threadIdx.x & 63;
  if (wid >= N_NODES) return;
  float di = dinv[wid], dd = di * di;
  unsigned int a = hbf_u[(size_t)wid * 64 + lane];
  float s0 = bflo(a) * dd, s1 = bfhi(a) * dd;
  int e = row_ptr[wid], end = row_ptr[wid + 1];
  for (; e < end; ++e) {
    int s = csr_src[e];
    float w = csr_w[e];
    unsigned int v = hbf_u[(size_t)s * 64 + lane];
    s0 += bflo(v) * w;
    s1 += bfhi(v) * w;
  }
  AhAc_u[(size_t)wid * 128 + 64 + lane] =
      (unsigned int)f2bf(s0) | ((unsigned int)f2bf(s1) << 16);
}

// ---------------- bf16 MFMA GEMM, K=256, A = AhAc [M][256] ----------------
// EPI 0 (init): v += b_init[col]; elu; col<128 -> hbf (bf16) else c_cur (fp32)
// EPI 1 (step): gate-interleaved cols; LSTM gates fused via LDS transpose
template <int EPI>
__global__ __launch_bounds__(256) void k_gemm(
    const unsigned short* __restrict__ A, const unsigned short* __restrict__ BT,
    const float* __restrict__ bias, float* __restrict__ c_cur,
    unsigned short* __restrict__ hbf, float* __restrict__ out_t) {
  __shared__ union {
    struct { unsigned short a[128 * 72]; unsigned short b[128 * 72]; } ab;
    float ep[64 * 132];
  } sm;
  const int M = N_NODES;
  int tid = threadIdx.x;
  int bm0 = blockIdx.x * 128, bn0 = blockIdx.y * 128;
  int wave = tid >> 6, lane = tid & 63;
  int wrow = (wave >> 1) * 64, wcol = (wave & 1) * 64;
  int lr = lane & 15, lq = lane >> 4;

  floatx4 acc[4][4];
#pragma unroll
  for (int i = 0; i < 4; i++)
#pragma unroll
    for (int j = 0; j < 4; j++) acc[i][j] = (floatx4){0.f, 0.f, 0.f, 0.f};

  for (int k0 = 0; k0 < 256; k0 += 64) {
    __syncthreads();
#pragma unroll
    for (int p = 0; p < 4; ++p) {
      int cch = tid + p * 256;  // 1024 chunks of 8 bf16
      int r = cch >> 3, c8 = (cch & 7) * 8;
      int grow = bm0 + r;
      float4 va = (grow < M) ? *(const float4*)(A + (size_t)grow * 256 + k0 + c8)
                             : (float4){0.f, 0.f, 0.f, 0.f};
      *(float4*)(sm.ab.a + r * 72 + c8) = va;
      float4 vb = *(const float4*)(BT + (size_t)(bn0 + r) * 256 + k0 + c8);
      *(float4*)(sm.ab.b + r * 72 + c8) = vb;
    }
    __syncthreads();
#pragma unroll
    for (int ks = 0; ks < 2; ++ks) {
      int kb = ks * 32 + lq * 8;
      bf16x8 af[4], bfr[4];
#pragma unroll
      for (int mi = 0; mi < 4; mi++)
        af[mi] = *(const bf16x8*)(sm.ab.a + (wrow + mi * 16 + lr) * 72 + kb);
#pragma unroll
      for (int ni = 0; ni < 4; ni++)
        bfr[ni] = *(const bf16x8*)(sm.ab.b + (wcol + ni * 16 + lr) * 72 + kb);
#pragma unroll
      for (int mi = 0; mi < 4; mi++)
#pragma unroll
        for (int ni = 0; ni < 4; ni++)
          acc[mi][ni] = __builtin_amdgcn_mfma_f32_16x16x32_bf16(
              af[mi], bfr[ni], acc[mi][ni], 0, 0, 0);
    }
  }
  __syncthreads();  // all waves done with sm.ab before epilogue reuse

  if (EPI == 0) {
#pragma unroll
    for (int mi = 0; mi < 4; mi++) {
#pragma unroll
      for (int r = 0; r < 4; r++) {
        int grow = bm0 + wrow + mi * 16 + lq * 4 + r;
        if (grow >= M) continue;
#pragma unroll
        for (int ni = 0; ni < 4; ni++) {
          int gcol = bn0 + wcol + ni * 16 + lr;
          float v = acc[mi][ni][r] + bias[gcol];
          v = (v > 0.f) ? v : expm1f(v);
          if (gcol < 128) hbf[(size_t)grow * 128 + gcol] = f2bf(v);
          else c_cur[(size_t)grow * 128 + gcol - 128] = v;
        }
      }
    }
  } else {
    // two 64-row chunks through LDS; gates applied per output j
#pragma unroll
    for (int hch = 0; hch < 2; ++hch) {
      if ((wrow >> 6) == hch) {
#pragma unroll
        for (int mi = 0; mi < 4; mi++)
#pragma unroll
          for (int r = 0; r < 4; r++) {
            int row_l = mi * 16 + lq * 4 + r;
#pragma unroll
            for (int ni = 0; ni < 4; ni++)
              sm.ep[row_l * 132 + wcol + ni * 16 + lr] = acc[mi][ni][r];
          }
      }
      __syncthreads();
#pragma unroll
      for (int it = 0; it < 8; ++it) {
        int p = tid + it * 256;
        int row_l = p >> 5, j = p & 31;
        int grow = bm0 + hch * 64 + row_l;
        if (grow < M) {
          int jg = (bn0 >> 2) + j;
          const float* eb = sm.ep + row_l * 132 + 4 * j;
          float gi = eb[0] + bias[jg];
          float gf = eb[1] + bias[128 + jg];
          float go = eb[2] + bias[256 + jg];
          float gg = eb[3] + bias[384 + jg];
          size_t o = (size_t)grow * 128 + jg;
          float cp = c_cur[o];
          float cn = sigf(gf) * cp + sigf(gi) * tanhf(gg);
          float hn = sigf(go) * tanhf(cn);
          c_cur[o] = cn;
          hbf[o] = f2bf(hn);
          out_t[o] = hn;
        }
      }
      __syncthreads();
    }
  }
}

// ---------------- host launcher ----------------
extern "C" void kernel_launch(void* const* d_in, const int* in_sizes, int n_in,
                              void* d_out, int out_size, void* d_ws, size_t ws_size,
                              hipStream_t stream) {
  const float* h  = (const float*)d_in[0];
  const float* c  = (const float*)d_in[1];
  const int*   ei = (const int*)d_in[2];
  const float* ea = (const float*)d_in[3];
  const float* Wi = (const float*)d_in[4];
  const float* bi = (const float*)d_in[5];
  const float* Wc = (const float*)d_in[6];
  const float* bc = (const float*)d_in[7];
  float* out = (float*)d_out;

  char* w = (char*)d_ws;
  size_t off = 0;
  auto alloc = [&](size_t bytes) {
    void* p = w + off;
    off += (bytes + 511) & ~(size_t)511;
    return p;
  };
  float* dinv          = (float*)alloc(N_NODES * 4);
  int* counts          = (int*)alloc(N_NODES * 4);
  int* cursor          = (int*)alloc(N_NODES * 4);
  int* scan_tmp        = (int*)alloc(N_NODES * 4);
  int* row_ptr         = (int*)alloc((N_NODES + 1) * 4);
  int* part            = (int*)alloc(1024 * 4);
  int* csr_src         = (int*)alloc(N_EDGES * 4);
  float* csr_w         = (float*)alloc(N_EDGES * 4);
  unsigned short* WiT  = (unsigned short*)alloc(256 * 256 * 2);
  unsigned short* WcT  = (unsigned short*)alloc(512 * 256 * 2);
  unsigned int* hc_bf  = (unsigned int*)alloc((size_t)N_NODES * 128 * 4);
  unsigned short* AhAc = (unsigned short*)alloc((size_t)N_NODES * 256 * 2);
  unsigned short* hbf  = (unsigned short*)alloc((size_t)N_NODES * 128 * 2);
  float* c_cur         = (float*)alloc((size_t)N_NODES * 128 * 4);

  const int NB_N = (N_NODES + 255) / 256;  // 79
  const int NB_E = (N_EDGES + 255) / 256;  // 1250
  const int NB_AGG = N_NODES * 64 / 256;   // 5000
  const int MB = (N_NODES + 127) / 128;    // 157

  k_init<<<NB_N, 256, 0, stream>>>(dinv, counts);
  k_deg<<<NB_E, 256, 0, stream>>>(ei, ea, dinv, counts);
  k_rsqrt<<<NB_N, 256, 0, stream>>>(dinv);
  k_scan1<<<NB_N, 256, 0, stream>>>(counts, scan_tmp, part);
  k_scan2<<<1, 128, 0, stream>>>(part, NB_N);
  k_scan3<<<NB_N, 256, 0, stream>>>(scan_tmp, counts, part, row_ptr, cursor);
  k_fill<<<NB_E, 256, 0, stream>>>(ei, ea, dinv, cursor, csr_src, csr_w);
  k_prep_w<<<512, 256, 0, stream>>>(Wi, Wc, WiT, WcT);
  k_cvt<<<(N_NODES * 128 + 255) / 256, 256, 0, stream>>>(h, c, hc_bf);

  k_agg_init<<<NB_AGG, 256, 0, stream>>>(hc_bf, (unsigned int*)AhAc, dinv,
                                         row_ptr, csr_src, csr_w);
  k_gemm<0><<<dim3(MB, 2), 256, 0, stream>>>(AhAc, WiT, bi, c_cur, hbf, nullptr);

  for (int t = 0; t < SEQ; ++t) {
    k_agg_step<<<NB_AGG, 256, 0, stream>>>((unsigned int*)hbf,
                                           (unsigned int*)AhAc, dinv, row_ptr,
                                           csr_src, csr_w);
    k_gemm<1><<<dim3(MB, 4), 256, 0, stream>>>(
        AhAc, WcT, bc, c_cur, hbf, out + (size_t)t * N_NODES * 128);
  }
}

// Round 3
// 742.785 us; speedup vs baseline: 1.1228x; 1.1228x over previous
//
#include <hip/hip_runtime.h>

#define N_NODES 20000
#define N_EDGES 320000
#define SEQ 8

typedef __attribute__((ext_vector_type(8))) short bf16x8;
typedef __attribute__((ext_vector_type(4))) float floatx4;

__device__ __forceinline__ unsigned short f2bf(float f) {
  unsigned int u = __builtin_bit_cast(unsigned int, f);
  return (unsigned short)((u + 0x7fffu + ((u >> 16) & 1u)) >> 16);
}
__device__ __forceinline__ float bflo(unsigned int u) {
  return __builtin_bit_cast(float, u << 16);
}
__device__ __forceinline__ float bfhi(unsigned int u) {
  return __builtin_bit_cast(float, u & 0xffff0000u);
}
__device__ __forceinline__ float sigf(float x) { return 1.f / (1.f + __expf(-x)); }

// ---------------- setup ----------------

// init deg/counts + transpose/convert weights, one launch (512 blocks x 256)
// WiT[n][k] = Wi[k][n] (256x256); WcT[n'][k] gate-interleaved: n'=4j+gate,
// orig = gate*128 + j
__global__ void k_prologue(const float* __restrict__ Wi,
                           const float* __restrict__ Wc,
                           unsigned short* __restrict__ WiT,
                           unsigned short* __restrict__ WcT,
                           float* __restrict__ deg, int* __restrict__ counts) {
  int idx = blockIdx.x * 256 + threadIdx.x;  // 0..131071
  if (idx < N_NODES) { deg[idx] = 1.0f; counts[idx] = 0; }
  if (idx < 65536) {
    int n = idx >> 8, k = idx & 255;
    WiT[n * 256 + k] = f2bf(Wi[k * 256 + n]);
  }
  int n2 = idx >> 8, k = idx & 255;  // n2 0..511
  int orig = ((n2 & 3) << 7) | (n2 >> 2);
  WcT[n2 * 256 + k] = f2bf(Wc[k * 512 + orig]);
}

__global__ void k_deg(const int* __restrict__ ei, const float* __restrict__ ea,
                      float* __restrict__ deg, int* __restrict__ counts) {
  int e = blockIdx.x * 256 + threadIdx.x;
  if (e >= N_EDGES) return;
  int d = ei[N_EDGES + e];
  atomicAdd(&deg[d], ea[e]);
  atomicAdd(&counts[d], 1);
}

// block-inclusive scan of counts + fold in dinv = rsqrt(deg)
__global__ void k_scan1(const int* __restrict__ counts, int* __restrict__ incl,
                        int* __restrict__ part, const float* __restrict__ deg,
                        float* __restrict__ dinv) {
  __shared__ int sm[256];
  int t = threadIdx.x;
  int g = blockIdx.x * 256 + t;
  if (g < N_NODES) dinv[g] = rsqrtf(deg[g]);
  int v = (g < N_NODES) ? counts[g] : 0;
  sm[t] = v;
  __syncthreads();
  for (int o = 1; o < 256; o <<= 1) {
    int add = (t >= o) ? sm[t - o] : 0;
    __syncthreads();
    sm[t] += add;
    __syncthreads();
  }
  if (g < N_NODES) incl[g] = sm[t];
  if (t == 255) part[blockIdx.x] = sm[255];
}

__global__ void k_scan2(int* __restrict__ part, int nb) {
  __shared__ int sm[128];
  int t = threadIdx.x;
  int v = (t < nb) ? part[t] : 0;
  sm[t] = v;
  __syncthreads();
  for (int o = 1; o < 128; o <<= 1) {
    int add = (t >= o) ? sm[t - o] : 0;
    __syncthreads();
    sm[t] += add;
    __syncthreads();
  }
  if (t < nb) part[t] = sm[t] - v;  // exclusive
}

__global__ void k_scan3(const int* __restrict__ incl, const int* __restrict__ counts,
                        const int* __restrict__ part, int* __restrict__ row_ptr,
                        int* __restrict__ cursor) {
  int g = blockIdx.x * 256 + threadIdx.x;
  if (g < N_NODES) {
    int start = incl[g] - counts[g] + part[blockIdx.x];
    row_ptr[g] = start;
    cursor[g] = start;
  }
  if (g == 0) row_ptr[N_NODES] = N_EDGES;
}

__global__ void k_fill(const int* __restrict__ ei, const float* __restrict__ ea,
                       const float* __restrict__ dinv, int* __restrict__ cursor,
                       int* __restrict__ csr_src, float* __restrict__ csr_w) {
  int e = blockIdx.x * 256 + threadIdx.x;
  if (e >= N_EDGES) return;
  int s = ei[e], d = ei[N_EDGES + e];
  int k = atomicAdd(&cursor[d], 1);
  csr_src[k] = s;
  csr_w[k] = dinv[s] * ea[e] * dinv[d];
}

// ---------------- aggregation (gather via CSR, one wave per node) -------------

// init: gather fp32 h,c directly. Lane l<32 covers h cols 4l..4l+3,
// lane>=32 covers c cols 4(l-32).. ; out = AhAc row (256 bf16, uint2/lane)
__global__ __launch_bounds__(256) void k_agg_init(
    const float* __restrict__ h, const float* __restrict__ c,
    unsigned int* __restrict__ AhAc_u, const float* __restrict__ dinv,
    const int* __restrict__ row_ptr, const int* __restrict__ csr_src,
    const float* __restrict__ csr_w) {
  int wid = (blockIdx.x * 256 + threadIdx.x) >> 6;
  int lane = threadIdx.x & 63;
  if (wid >= N_NODES) return;
  float di = dinv[wid], dd = di * di;
  const float4* xb = (lane < 32) ? (const float4*)h : (const float4*)c;
  int lcol = lane & 31;
  float4 a = xb[(size_t)wid * 32 + lcol];
  float s0 = a.x * dd, s1 = a.y * dd, s2 = a.z * dd, s3 = a.w * dd;
  int e = row_ptr[wid], end = row_ptr[wid + 1];
#pragma unroll 2
  for (; e < end; ++e) {
    int s = csr_src[e];
    float w = csr_w[e];
    float4 v = xb[(size_t)s * 32 + lcol];
    s0 += v.x * w; s1 += v.y * w; s2 += v.z * w; s3 += v.w * w;
  }
  uint2 o;
  o.x = (unsigned int)f2bf(s0) | ((unsigned int)f2bf(s1) << 16);
  o.y = (unsigned int)f2bf(s2) | ((unsigned int)f2bf(s3) << 16);
  ((uint2*)AhAc_u)[(size_t)wid * 64 + lane] = o;
}

// step: x = hbf rows of 128 bf16 (uint/lane); out -> AhAc cols 128..255
__global__ __launch_bounds__(256) void k_agg_step(
    const unsigned int* __restrict__ hbf_u, unsigned int* __restrict__ AhAc_u,
    const float* __restrict__ dinv, const int* __restrict__ row_ptr,
    const int* __restrict__ csr_src, const float* __restrict__ csr_w) {
  int wid = (blockIdx.x * 256 + threadIdx.x) >> 6;
  int lane = threadIdx.x & 63;
  if (wid >= N_NODES) return;
  float di = dinv[wid], dd = di * di;
  unsigned int a = hbf_u[(size_t)wid * 64 + lane];
  float s0 = bflo(a) * dd, s1 = bfhi(a) * dd;
  int e = row_ptr[wid], end = row_ptr[wid + 1];
#pragma unroll 2
  for (; e < end; ++e) {
    int s = csr_src[e];
    float w = csr_w[e];
    unsigned int v = hbf_u[(size_t)s * 64 + lane];
    s0 += bflo(v) * w;
    s1 += bfhi(v) * w;
  }
  AhAc_u[(size_t)wid * 128 + 64 + lane] =
      (unsigned int)f2bf(s0) | ((unsigned int)f2bf(s1) << 16);
}

// ---------------- bf16 MFMA GEMM, K=256, A = AhAc [M][256] ----------------
// EPI 0 (init): v += b_init[col]; elu; col<128 -> hbf (bf16) else c_cur (fp32)
// EPI 1 (step): gate-interleaved cols; LSTM gates fused via LDS transpose
template <int EPI>
__global__ __launch_bounds__(256) void k_gemm(
    const unsigned short* __restrict__ A, const unsigned short* __restrict__ BT,
    const float* __restrict__ bias, float* __restrict__ c_cur,
    unsigned short* __restrict__ hbf, float* __restrict__ out_t) {
  __shared__ union {
    struct { unsigned short a[128 * 72]; unsigned short b[128 * 72]; } ab;
    float ep[64 * 132];
  } sm;
  const int M = N_NODES;
  int tid = threadIdx.x;
  int bm0 = blockIdx.x * 128, bn0 = blockIdx.y * 128;
  int wave = tid >> 6, lane = tid & 63;
  int wrow = (wave >> 1) * 64, wcol = (wave & 1) * 64;
  int lr = lane & 15, lq = lane >> 4;

  floatx4 acc[4][4];
#pragma unroll
  for (int i = 0; i < 4; i++)
#pragma unroll
    for (int j = 0; j < 4; j++) acc[i][j] = (floatx4){0.f, 0.f, 0.f, 0.f};

  for (int k0 = 0; k0 < 256; k0 += 64) {
    __syncthreads();
#pragma unroll
    for (int p = 0; p < 4; ++p) {
      int cch = tid + p * 256;  // 1024 chunks of 8 bf16
      int r = cch >> 3, c8 = (cch & 7) * 8;
      int grow = bm0 + r;
      float4 va = (grow < M) ? *(const float4*)(A + (size_t)grow * 256 + k0 + c8)
                             : (float4){0.f, 0.f, 0.f, 0.f};
      *(float4*)(sm.ab.a + r * 72 + c8) = va;
      float4 vb = *(const float4*)(BT + (size_t)(bn0 + r) * 256 + k0 + c8);
      *(float4*)(sm.ab.b + r * 72 + c8) = vb;
    }
    __syncthreads();
#pragma unroll
    for (int ks = 0; ks < 2; ++ks) {
      int kb = ks * 32 + lq * 8;
      bf16x8 af[4], bfr[4];
#pragma unroll
      for (int mi = 0; mi < 4; mi++)
        af[mi] = *(const bf16x8*)(sm.ab.a + (wrow + mi * 16 + lr) * 72 + kb);
#pragma unroll
      for (int ni = 0; ni < 4; ni++)
        bfr[ni] = *(const bf16x8*)(sm.ab.b + (wcol + ni * 16 + lr) * 72 + kb);
#pragma unroll
      for (int mi = 0; mi < 4; mi++)
#pragma unroll
        for (int ni = 0; ni < 4; ni++)
          acc[mi][ni] = __builtin_amdgcn_mfma_f32_16x16x32_bf16(
              af[mi], bfr[ni], acc[mi][ni], 0, 0, 0);
    }
  }
  __syncthreads();  // all waves done with sm.ab before epilogue reuse

  if (EPI == 0) {
#pragma unroll
    for (int mi = 0; mi < 4; mi++) {
#pragma unroll
      for (int r = 0; r < 4; r++) {
        int grow = bm0 + wrow + mi * 16 + lq * 4 + r;
        if (grow >= M) continue;
#pragma unroll
        for (int ni = 0; ni < 4; ni++) {
          int gcol = bn0 + wcol + ni * 16 + lr;
          float v = acc[mi][ni][r] + bias[gcol];
          v = (v > 0.f) ? v : expm1f(v);
          if (gcol < 128) hbf[(size_t)grow * 128 + gcol] = f2bf(v);
          else c_cur[(size_t)grow * 128 + gcol - 128] = v;
        }
      }
    }
  } else {
    // two 64-row chunks through LDS; gates applied per output j
#pragma unroll
    for (int hch = 0; hch < 2; ++hch) {
      if ((wrow >> 6) == hch) {
#pragma unroll
        for (int mi = 0; mi < 4; mi++)
#pragma unroll
          for (int r = 0; r < 4; r++) {
            int row_l = mi * 16 + lq * 4 + r;
#pragma unroll
            for (int ni = 0; ni < 4; ni++)
              sm.ep[row_l * 132 + wcol + ni * 16 + lr] = acc[mi][ni][r];
          }
      }
      __syncthreads();
#pragma unroll
      for (int it = 0; it < 8; ++it) {
        int p = tid + it * 256;
        int row_l = p >> 5, j = p & 31;
        int grow = bm0 + hch * 64 + row_l;
        if (grow < M) {
          int jg = (bn0 >> 2) + j;
          const float* eb = sm.ep + row_l * 132 + 4 * j;
          float gi = eb[0] + bias[jg];
          float gf = eb[1] + bias[128 + jg];
          float go = eb[2] + bias[256 + jg];
          float gg = eb[3] + bias[384 + jg];
          size_t o = (size_t)grow * 128 + jg;
          float cp = c_cur[o];
          float cn = sigf(gf) * cp + sigf(gi) * tanhf(gg);
          float hn = sigf(go) * tanhf(cn);
          c_cur[o] = cn;
          hbf[o] = f2bf(hn);
          out_t[o] = hn;
        }
      }
      __syncthreads();
    }
  }
}

// ---------------- host launcher ----------------
extern "C" void kernel_launch(void* const* d_in, const int* in_sizes, int n_in,
                              void* d_out, int out_size, void* d_ws, size_t ws_size,
                              hipStream_t stream) {
  const float* h  = (const float*)d_in[0];
  const float* c  = (const float*)d_in[1];
  const int*   ei = (const int*)d_in[2];
  const float* ea = (const float*)d_in[3];
  const float* Wi = (const float*)d_in[4];
  const float* bi = (const float*)d_in[5];
  const float* Wc = (const float*)d_in[6];
  const float* bc = (const float*)d_in[7];
  float* out = (float*)d_out;

  char* w = (char*)d_ws;
  size_t off = 0;
  auto alloc = [&](size_t bytes) {
    void* p = w + off;
    off += (bytes + 511) & ~(size_t)511;
    return p;
  };
  float* deg           = (float*)alloc(N_NODES * 4);
  float* dinv          = (float*)alloc(N_NODES * 4);
  int* counts          = (int*)alloc(N_NODES * 4);
  int* cursor          = (int*)alloc(N_NODES * 4);
  int* scan_tmp        = (int*)alloc(N_NODES * 4);
  int* row_ptr         = (int*)alloc((N_NODES + 1) * 4);
  int* part            = (int*)alloc(1024 * 4);
  int* csr_src         = (int*)alloc(N_EDGES * 4);
  float* csr_w         = (float*)alloc(N_EDGES * 4);
  unsigned short* WiT  = (unsigned short*)alloc(256 * 256 * 2);
  unsigned short* WcT  = (unsigned short*)alloc(512 * 256 * 2);
  unsigned short* AhAc = (unsigned short*)alloc((size_t)N_NODES * 256 * 2);
  unsigned short* hbf  = (unsigned short*)alloc((size_t)N_NODES * 128 * 2);
  float* c_cur         = (float*)alloc((size_t)N_NODES * 128 * 4);

  const int NB_N = (N_NODES + 255) / 256;  // 79
  const int NB_E = (N_EDGES + 255) / 256;  // 1250
  const int NB_AGG = N_NODES * 64 / 256;   // 5000
  const int MB = (N_NODES + 127) / 128;    // 157

  k_prologue<<<512, 256, 0, stream>>>(Wi, Wc, WiT, WcT, deg, counts);
  k_deg<<<NB_E, 256, 0, stream>>>(ei, ea, deg, counts);
  k_scan1<<<NB_N, 256, 0, stream>>>(counts, scan_tmp, part, deg, dinv);
  k_scan2<<<1, 128, 0, stream>>>(part, NB_N);
  k_scan3<<<NB_N, 256, 0, stream>>>(scan_tmp, counts, part, row_ptr, cursor);
  k_fill<<<NB_E, 256, 0, stream>>>(ei, ea, dinv, cursor, csr_src, csr_w);

  k_agg_init<<<NB_AGG, 256, 0, stream>>>(h, c, (unsigned int*)AhAc, dinv,
                                         row_ptr, csr_src, csr_w);
  k_gemm<0><<<dim3(MB, 2), 256, 0, stream>>>(AhAc, WiT, bi, c_cur, hbf, nullptr);

  for (int t = 0; t < SEQ; ++t) {
    k_agg_step<<<NB_AGG, 256, 0, stream>>>((unsigned int*)hbf,
                                           (unsigned int*)AhAc, dinv, row_ptr,
                                           csr_src, csr_w);
    k_gemm<1><<<dim3(MB, 4), 256, 0, stream>>>(
        AhAc, WcT, bc, c_cur, hbf, out + (size_t)t * N_NODES * 128);
  }
}